// Round 1
// 239.925 us; speedup vs baseline: 1.0521x; 1.0521x over previous
//
#include <hip/hip_runtime.h>
#include <hip/hip_bf16.h>
#include <math.h>

#define NH 8
#define HD 64
#define CH 512
#define NT 1024
#define NB 8

typedef __bf16 bf16_t;
typedef bf16_t bf16x8 __attribute__((ext_vector_type(8)));
typedef bf16_t bf16x4 __attribute__((ext_vector_type(4)));
typedef float  f32x4  __attribute__((ext_vector_type(4)));
typedef float  f32x16 __attribute__((ext_vector_type(16)));
typedef unsigned u32x4 __attribute__((ext_vector_type(4)));

#define MFMA16(a, b, c) __builtin_amdgcn_mfma_f32_16x16x32_bf16((a), (b), (c), 0, 0, 0)
#define MFMA32(a, b, c) __builtin_amdgcn_mfma_f32_32x32x16_bf16((a), (b), (c), 0, 0, 0)

__device__ __forceinline__ void gload16(const void* g, void* l) {
    __builtin_amdgcn_global_load_lds(
        (const __attribute__((address_space(1))) void*)g,
        (__attribute__((address_space(3))) void*)l, 16, 0, 0);
}

// pack two f32 -> one dword of 2x bf16 (no builtin on gfx950; T12 recipe)
__device__ __forceinline__ unsigned cvtpk(float lo, float hi) {
    unsigned r;
    asm("v_cvt_pk_bf16_f32 %0, %1, %2" : "=v"(r) : "v"(lo), "v"(hi));
    return r;
}

// v_permlane32_swap_b32: a' = {a.lo32, b.lo32}, b' = {a.hi32, b.hi32}
__device__ __forceinline__ void plswap(unsigned& a, unsigned& b) {
    asm("v_permlane32_swap_b32 %0, %1" : "+v"(a), "+v"(b));
}

// ---------------------------------------------------------------------------
// prep: fp32 [C][N] -> bf16 [N][C] transpose (per 64x64 tile).
// grid (128, 24): x = tile (c-tile = x&7, n-tile = x>>3); y: b = y/3, ft = y%3
// ---------------------------------------------------------------------------
__global__ __launch_bounds__(256) void prep_kernel(
    const float* __restrict__ fc, const float* __restrict__ fp,
    const float* __restrict__ fn, bf16_t* __restrict__ Xc,
    bf16_t* __restrict__ Xn)
{
    __shared__ __align__(16) bf16_t tile[64 * 64];
    const int t = threadIdx.x;
    const int y = blockIdx.y;
    const int b = y / 3, ft = y % 3;
    const int c0 = (blockIdx.x & 7) * 64;
    const int n0 = (blockIdx.x >> 3) * 64;

    const float* src; bf16_t* dst;
    if (ft == 0)      { src = fc + (size_t)b * CH * NT; dst = Xc + (size_t)b * NT * CH; }
    else if (ft == 1) { src = fp + (size_t)b * CH * NT; dst = Xn + (size_t)b * 2 * NT * CH; }
    else              { src = fn + (size_t)b * CH * NT; dst = Xn + (size_t)b * 2 * NT * CH + (size_t)NT * CH; }

    const int nb = t & 15, cb = t >> 4;   // 4-wide chunks
    float4 ld[4];
#pragma unroll
    for (int i = 0; i < 4; ++i)
        ld[i] = *(const float4*)(src + (size_t)(c0 + cb * 4 + i) * NT + n0 + nb * 4);
    const float* lf = (const float*)ld;
#pragma unroll
    for (int j = 0; j < 4; ++j) {
        int n = nb * 4 + j;
        int v = (n >> 2) & 14;            // even -> bf16x8 readback stays contiguous
        bf16x4 wv = { (bf16_t)lf[0 * 4 + j], (bf16_t)lf[1 * 4 + j],
                      (bf16_t)lf[2 * 4 + j], (bf16_t)lf[3 * 4 + j] };
        *(bf16x4*)(tile + n * 64 + ((cb ^ v) * 4)) = wv;
    }
    __syncthreads();
#pragma unroll
    for (int i = 0; i < 2; ++i) {
        int gid = t + i * 256;            // 512 chunks of 16B
        int n = gid >> 3, c16 = gid & 7;
        int v = (n >> 2) & 14;
        bf16x8 val = *(const bf16x8*)(tile + n * 64 + (((2 * c16) ^ v) * 4));
        *(bf16x8*)(dst + (size_t)(n0 + n) * CH + c0 + c16 * 8) = val;
    }
}

// weights fp32 -> bf16, grid (256, 4)
__global__ __launch_bounds__(256) void wcvt_kernel(
    const float* __restrict__ Wq, const float* __restrict__ Wk,
    const float* __restrict__ Wv, const float* __restrict__ Wo,
    bf16_t* __restrict__ Wb)
{
    const int m = blockIdx.y;
    const float* src = (m == 0) ? Wq : (m == 1) ? Wk : (m == 2) ? Wv : Wo;
    bf16_t* dst = Wb + (size_t)m * CH * CH;
    int gid = blockIdx.x * 256 + threadIdx.x;      // 65536 float4 per matrix
    float4 v = *(const float4*)(src + (size_t)gid * 4);
    bf16x4 o = { (bf16_t)v.x, (bf16_t)v.y, (bf16_t)v.z, (bf16_t)v.w };
    *(bf16x4*)(dst + (size_t)gid * 4) = o;
}

// ---------------------------------------------------------------------------
// gemm_core: 128x128 tile, K=512, BK=32, all-bf16, global_load_lds staging.
// ---------------------------------------------------------------------------
template <bool SWAP>
__device__ __forceinline__ void gemm_core(const bf16_t* __restrict__ A,
                                          const bf16_t* __restrict__ B,
                                          bf16_t* aT, bf16_t* bT,
                                          f32x4 acc[4][4])
{
    const int t = threadIdx.x, w = t >> 6, lane = t & 63;
    const int lid = lane & 15, quad = lane >> 4;
    const int wm = w >> 1, wn = w & 1;
    const int l4 = lane >> 2, k4 = lane & 3;

    for (int kt = 0; kt < 16; ++kt) {
        const int k0 = kt * 32;
        __syncthreads();
#pragma unroll
        for (int i = 0; i < 2; ++i) {
            int q = w * 2 + i;                       // chunk 0..7 (16 rows each)
            int row = q * 16 + l4;
            int kk = k4 ^ ((row >> 1) & 3);
            gload16(A + (size_t)row * CH + k0 + kk * 8, aT + q * 512);
            gload16(B + (size_t)row * CH + k0 + kk * 8, bT + q * 512);
        }
        __syncthreads();

        const bf16_t* mT = SWAP ? bT : aT;
        const bf16_t* nT = SWAP ? aT : bT;
        bf16x8 mf[4], nf[4];
#pragma unroll
        for (int i = 0; i < 4; ++i) {
            int row = wm * 64 + i * 16 + lid;
            int kw = quad ^ ((row >> 1) & 3);
            mf[i] = *(const bf16x8*)(mT + row * 32 + kw * 8);
        }
#pragma unroll
        for (int i = 0; i < 4; ++i) {
            int row = wn * 64 + i * 16 + lid;
            int kw = quad ^ ((row >> 1) & 3);
            nf[i] = *(const bf16x8*)(nT + row * 32 + kw * 8);
        }
#pragma unroll
        for (int mi = 0; mi < 4; ++mi)
#pragma unroll
            for (int ni = 0; ni < 4; ++ni)
                acc[mi][ni] = MFMA16(mf[mi], nf[ni], acc[mi][ni]);
    }
}

// ---------------------------------------------------------------------------
// qkv: grid (160, 8).  bx<32: Q; 32..95: K; 96..159: V (SWAP, writes Vt[co][key])
// ---------------------------------------------------------------------------
__global__ __launch_bounds__(256) void qkv_kernel(
    const bf16_t* __restrict__ Xc, const bf16_t* __restrict__ Xn,
    const bf16_t* __restrict__ Wb,
    bf16_t* __restrict__ Qn, bf16_t* __restrict__ Kn, bf16_t* __restrict__ Vt)
{
    __shared__ __align__(16) bf16_t aT[128 * 32];
    __shared__ __align__(16) bf16_t bT[128 * 32];
    const int bx = blockIdx.x, b = blockIdx.y;
    const int t = threadIdx.x, w = t >> 6, lane = t & 63;
    const int lid = lane & 15, quad = lane >> 4;
    const int wm = w >> 1, wn = w & 1;
    const float QSC = 0.125f * 1.44269504f;

    f32x4 acc[4][4] = {};

    if (bx < 96) {                        // Q or K job
        const bf16_t* A; const bf16_t* B; bf16_t* O; float scale;
        if (bx < 32) {
            int nt = bx >> 2, ct = bx & 3;
            A = Xc + (size_t)b * NT * CH + (size_t)nt * 128 * CH;
            B = Wb + (size_t)0 * CH * CH + (size_t)ct * 128 * CH;
            O = Qn + (size_t)b * NT * CH + (size_t)nt * 128 * CH + ct * 128;
            scale = QSC;
        } else {
            int j = bx - 32, nt = j >> 2, ct = j & 3;
            A = Xn + (size_t)b * 2 * NT * CH + (size_t)nt * 128 * CH;
            B = Wb + (size_t)1 * CH * CH + (size_t)ct * 128 * CH;
            O = Kn + (size_t)b * 2 * NT * CH + (size_t)nt * 128 * CH + ct * 128;
            scale = 1.0f;
        }
        gemm_core<false>(A, B, aT, bT, acc);
#pragma unroll
        for (int mi = 0; mi < 4; ++mi)
#pragma unroll
            for (int ni = 0; ni < 4; ++ni)
#pragma unroll
                for (int r = 0; r < 4; ++r) {
                    int n  = wm * 64 + mi * 16 + quad * 4 + r;
                    int co = wn * 64 + ni * 16 + lid;
                    O[(size_t)n * CH + co] = (bf16_t)(acc[mi][ni][r] * scale);
                }
    } else {                              // V job -> Vt[co][key]
        int j = bx - 96, nt = j >> 2, ct = j & 3;
        const bf16_t* A = Xn + (size_t)b * 2 * NT * CH + (size_t)nt * 128 * CH;
        const bf16_t* B = Wb + (size_t)2 * CH * CH + (size_t)ct * 128 * CH;
        bf16_t* O = Vt + (size_t)b * CH * 2 * NT + (size_t)ct * 128 * 2 * NT + nt * 128;
        gemm_core<true>(A, B, aT, bT, acc);
#pragma unroll
        for (int mi = 0; mi < 4; ++mi)
#pragma unroll
            for (int ni = 0; ni < 4; ++ni)
#pragma unroll
                for (int r = 0; r < 4; ++r) {
                    int co_l  = wm * 64 + mi * 16 + quad * 4 + r;
                    int key_l = wn * 64 + ni * 16 + lid;
                    O[(size_t)co_l * (2 * NT) + key_l] = (bf16_t)acc[mi][ni][r];
                }
    }
}

// ---------------------------------------------------------------------------
// attn v2: S^T formulation, 32x32x16 MFMA, no-max softmax.
//  - P stays in registers: exp2 -> v_cvt_pk_bf16_f32 -> v_permlane32_swap_b32
//    builds the PV B-fragment directly (S^T col=query already = B col).
//  - K and V each double-buffered in LDS -> ONE barrier per K-tile (was 4).
//  - XCD-grouped block swizzle: all 8 q-tiles of one (b,h) share one XCD L2
//    (512KB K/V x 8 resident groups = 4MB = L2). grid = 512 linear blocks.
//  - s_setprio(1) around MFMA clusters; softmax(mf) interleaved with PV(mf).
// LDS 72192B -> 2 blocks/CU (same as before).
// ---------------------------------------------------------------------------
__global__ __launch_bounds__(256, 2) void attn_kernel(
    const bf16_t* __restrict__ Qn, const bf16_t* __restrict__ Kn,
    const bf16_t* __restrict__ Vt, bf16_t* __restrict__ AOn)
{
    __shared__ __align__(16) char smem[72192];
    bf16_t* const kbuf0 = (bf16_t*)smem;                 // [128][72] bf16
    bf16_t* const kbuf1 = (bf16_t*)(smem + 18432);       // [128][72]
    bf16_t* const vbuf0 = (bf16_t*)(smem + 36864);       // [64][136]
    bf16_t* const vbuf1 = (bf16_t*)(smem + 54272);       // [64][136]
    float*  const l_scr = (float*)(smem + 71680);        // 128 f32

    const int t = threadIdx.x;
    const int w = t >> 6, lane = t & 63;
    const int wq = w >> 1, wk = w & 1;
    const int l31 = lane & 31, h = lane >> 5;

    // XCD-aware decode (XCD = linear bid % 8 round-robin):
    // group g = (b,h) pinned to one XCD; qtile varies within the XCD.
    const int bid = blockIdx.x;
    const int xcd = bid & 7, ii = bid >> 3;      // ii: 0..63
    const int grp = xcd * 8 + (ii >> 3);         // 0..63
    const int qt  = ii & 7;
    const int b = grp >> 3, hh = grp & 7;
    const int q0 = qt * 128;

    const bf16_t* Qb  = Qn + ((size_t)b * NT + q0) * CH + hh * HD;
    const bf16_t* Kb  = Kn + (size_t)b * 2 * NT * CH + hh * HD;
    const bf16_t* Vtb = Vt + ((size_t)b * CH + hh * HD) * (2 * NT);
    bf16_t* AOb = AOn + ((size_t)b * NT + q0) * CH + hh * HD;

    // ---- prologue: stage Q -> kbuf1, tile0 K/V -> buf0 --------------------
    bf16x8 kreg[4], vreg[4];
#pragma unroll
    for (int i = 0; i < 4; ++i) {
        int gid = t + i * 256;
        int qr = gid >> 3, c8 = (gid & 7) * 8;
        *(bf16x8*)(kbuf1 + qr * 72 + (c8 ^ (qr & 24))) =
            *(const bf16x8*)(Qb + (size_t)qr * CH + c8);
    }
#pragma unroll
    for (int i = 0; i < 4; ++i) {
        int gid = t + i * 256;
        int kr = gid >> 3, c8 = (gid & 7) * 8;
        kreg[i] = *(const bf16x8*)(Kb + (size_t)kr * CH + c8);
        int dr = gid >> 4, c16 = (gid & 15) * 8;
        vreg[i] = *(const bf16x8*)(Vtb + (size_t)dr * (2 * NT) + c16);
    }
#pragma unroll
    for (int i = 0; i < 4; ++i) {
        int gid = t + i * 256;
        int kr = gid >> 3, c8 = (gid & 7) * 8;
        *(bf16x8*)(kbuf0 + kr * 72 + (c8 ^ (kr & 24))) = kreg[i];
        int dr = gid >> 4, c16 = (gid & 15) * 8;
        *(bf16x8*)(vbuf0 + dr * 136 + (c16 ^ (dr & 24))) = vreg[i];
    }
    __syncthreads();

    bf16x8 qf[2][4];
#pragma unroll
    for (int nf = 0; nf < 2; ++nf)
#pragma unroll
        for (int ks = 0; ks < 4; ++ks) {
            int row = wq * 64 + nf * 32 + l31;
            int col = (ks * 16 + h * 8) ^ (row & 24);
            qf[nf][ks] = *(const bf16x8*)(kbuf1 + row * 72 + col);
        }
    // prefetch tile 1 into regs
#pragma unroll
    for (int i = 0; i < 4; ++i) {
        int gid = t + i * 256;
        int kr = gid >> 3, c8 = (gid & 7) * 8;
        kreg[i] = *(const bf16x8*)(Kb + (size_t)(128 + kr) * CH + c8);
        int dr = gid >> 4, c16 = (gid & 15) * 8;
        vreg[i] = *(const bf16x8*)(Vtb + (size_t)dr * (2 * NT) + 128 + c16);
    }
    __syncthreads();   // qf read done; buf1 free

    f32x16 o[2][2] = {};
    float lpart[2] = {0.f, 0.f};

    for (int kt = 0; kt < 16; ++kt) {
        const int cur = kt & 1;
        bf16_t* const kb_w = cur ? kbuf0 : kbuf1;
        bf16_t* const vb_w = cur ? vbuf0 : vbuf1;
        const bf16_t* const kb_r = cur ? kbuf1 : kbuf0;
        const bf16_t* const vb_r = cur ? vbuf1 : vbuf0;

        // stage tile kt+1 (regs -> LDS); prev reads of these buffers done at
        // the barrier ending iter kt-1.
#pragma unroll
        for (int i = 0; i < 4; ++i) {
            int gid = t + i * 256;
            int kr = gid >> 3, c8 = (gid & 7) * 8;
            *(bf16x8*)(kb_w + kr * 72 + (c8 ^ (kr & 24))) = kreg[i];
            int dr = gid >> 4, c16 = (gid & 15) * 8;
            *(bf16x8*)(vb_w + dr * 136 + (c16 ^ (dr & 24))) = vreg[i];
        }
        // prefetch tile kt+2 (clamped; last writes are junk, never read)
        {
            const int pfb = (kt + 2 < 16) ? (kt + 2) * 128 : 0;
#pragma unroll
            for (int i = 0; i < 4; ++i) {
                int gid = t + i * 256;
                int kr = gid >> 3, c8 = (gid & 7) * 8;
                kreg[i] = *(const bf16x8*)(Kb + (size_t)(pfb + kr) * CH + c8);
                int dr = gid >> 4, c16 = (gid & 15) * 8;
                vreg[i] = *(const bf16x8*)(Vtb + (size_t)dr * (2 * NT) + pfb + c16);
            }
        }

        // ---- S^T = K * Q  (rows=keys, cols=queries) -----------------------
        f32x16 s[2][2] = {};
        __builtin_amdgcn_s_setprio(1);
#pragma unroll
        for (int ks = 0; ks < 4; ++ks) {
            bf16x8 af[2];
#pragma unroll
            for (int mf = 0; mf < 2; ++mf) {
                int arow = wk * 64 + mf * 32 + l31;
                int acol = (ks * 16 + h * 8) ^ (arow & 24);
                af[mf] = *(const bf16x8*)(kb_r + arow * 72 + acol);
            }
#pragma unroll
            for (int mf = 0; mf < 2; ++mf)
#pragma unroll
                for (int nf = 0; nf < 2; ++nf)
                    s[mf][nf] = MFMA32(af[mf], qf[nf][ks], s[mf][nf]);
        }
        __builtin_amdgcn_s_setprio(0);

        // ---- softmax(mf) in registers, then PV(mf) ------------------------
        // S^T reg r at lane(l31=q, h): key = (r&3) + 8*(r>>2) + 4*h.
        // PV B-fragment (32x32x16): col=q=l31, k = 8*h + e.  The permlane
        // swap moves the partner half's 4-key groups into place.
#pragma unroll
        for (int mf = 0; mf < 2; ++mf) {
            bf16x8 pfrag[2][2];                  // [nf][fi]  fi: 16-key half
#pragma unroll
            for (int nf = 0; nf < 2; ++nf) {
                float p[16];
#pragma unroll
                for (int r = 0; r < 16; ++r) p[r] = exp2f(s[mf][nf][r]);
                lpart[nf] += ((p[0] + p[1]) + (p[2] + p[3]))
                           + ((p[4] + p[5]) + (p[6] + p[7]))
                           + ((p[8] + p[9]) + (p[10] + p[11]))
                           + ((p[12] + p[13]) + (p[14] + p[15]));
                unsigned a0 = cvtpk(p[0], p[1]),   b0 = cvtpk(p[4], p[5]);
                unsigned a1 = cvtpk(p[2], p[3]),   b1 = cvtpk(p[6], p[7]);
                unsigned a2 = cvtpk(p[8], p[9]),   b2 = cvtpk(p[12], p[13]);
                unsigned a3 = cvtpk(p[10], p[11]), b3 = cvtpk(p[14], p[15]);
                plswap(a0, b0); plswap(a1, b1); plswap(a2, b2); plswap(a3, b3);
                u32x4 f0 = { a0, a1, b0, b1 };
                u32x4 f1 = { a2, a3, b2, b3 };
                pfrag[nf][0] = __builtin_bit_cast(bf16x8, f0);
                pfrag[nf][1] = __builtin_bit_cast(bf16x8, f1);
            }
            __builtin_amdgcn_s_setprio(1);
#pragma unroll
            for (int fi = 0; fi < 2; ++fi) {
                const int ks = mf * 2 + fi;
                bf16x8 av[2];
#pragma unroll
                for (int df = 0; df < 2; ++df) {
                    int vrow = df * 32 + l31;
                    int vcol = (wk * 64 + ks * 16 + h * 8) ^ (vrow & 24);
                    av[df] = *(const bf16x8*)(vb_r + vrow * 136 + vcol);
                }
#pragma unroll
                for (int df = 0; df < 2; ++df)
#pragma unroll
                    for (int nf = 0; nf < 2; ++nf)
                        o[df][nf] = MFMA32(av[df], pfrag[nf][fi], o[df][nf]);
            }
            __builtin_amdgcn_s_setprio(0);
        }
        __syncthreads();   // buf[cur] reads done; buf[cur^1] writes visible
    }

    // ---- epilogue: combine wk halves, normalize, store --------------------
    float l2[2];
#pragma unroll
    for (int nf = 0; nf < 2; ++nf)
        l2[nf] = lpart[nf] + __shfl_xor(lpart[nf], 32);

    float* const scr_all = (float*)smem;               // 2 x 4352 f32 (34816B)
    bf16_t* const obuf = (bf16_t*)(smem + 36864);      // [128][72] bf16

    if (wk == 1) {
        float* scr = scr_all + wq * 4352;
#pragma unroll
        for (int df = 0; df < 2; ++df)
#pragma unroll
            for (int nf = 0; nf < 2; ++nf) {
                int qrow = nf * 32 + l31;
#pragma unroll
                for (int g = 0; g < 4; ++g) {
                    int d = df * 32 + 8 * g + 4 * h;
                    f32x4 v = { o[df][nf][4 * g + 0], o[df][nf][4 * g + 1],
                                o[df][nf][4 * g + 2], o[df][nf][4 * g + 3] };
                    *(f32x4*)(scr + qrow * 68 + d) = v;
                }
            }
        if (h == 0) {
            l_scr[wq * 64 + 0 * 32 + l31] = l2[0];
            l_scr[wq * 64 + 1 * 32 + l31] = l2[1];
        }
    }
    __syncthreads();

    if (wk == 0) {
        const float* scr = scr_all + wq * 4352;
        float inv[2];
#pragma unroll
        for (int nf = 0; nf < 2; ++nf)
            inv[nf] = 1.0f / (l2[nf] + l_scr[wq * 64 + nf * 32 + l31]);
#pragma unroll
        for (int df = 0; df < 2; ++df)
#pragma unroll
            for (int nf = 0; nf < 2; ++nf) {
                int qrow = nf * 32 + l31;
#pragma unroll
                for (int g = 0; g < 4; ++g) {
                    int d = df * 32 + 8 * g + 4 * h;
                    f32x4 part = *(const f32x4*)(scr + qrow * 68 + d);
                    bf16x4 ov = {
                        (bf16_t)((o[df][nf][4 * g + 0] + part.x) * inv[nf]),
                        (bf16_t)((o[df][nf][4 * g + 1] + part.y) * inv[nf]),
                        (bf16_t)((o[df][nf][4 * g + 2] + part.z) * inv[nf]),
                        (bf16_t)((o[df][nf][4 * g + 3] + part.w) * inv[nf]) };
                    int qg = wq * 64 + qrow;
                    *(bf16x4*)(obuf + qg * 72 + (d ^ (qg & 24))) = ov;
                }
            }
    }
    __syncthreads();

#pragma unroll
    for (int i = 0; i < 4; ++i) {
        int gid = t + i * 256;
        int qr = gid >> 3, c8 = (gid & 7) * 8;
        *(bf16x8*)(AOb + (size_t)qr * CH + c8) =
            *(const bf16x8*)(obuf + qr * 72 + (c8 ^ (qr & 24)));
    }
}

// ---------------------------------------------------------------------------
// proj: Z^T[b][co][n] = (AO @ Wo^T)^T + f_curr[b][co][n]  (fp32). grid (32, 8)
// ---------------------------------------------------------------------------
__global__ __launch_bounds__(256) void proj_kernel(
    const bf16_t* __restrict__ AOn, const bf16_t* __restrict__ Wb,
    const float* __restrict__ fc, float* __restrict__ Zt)
{
    __shared__ __align__(16) bf16_t aT[128 * 32];
    __shared__ __align__(16) bf16_t bT[128 * 32];
    const int bx = blockIdx.x, b = blockIdx.y;
    const int nt = bx >> 2, ct = bx & 3;
    const int t = threadIdx.x, w = t >> 6, lane = t & 63;
    const int lid = lane & 15, quad = lane >> 4;
    const int wm = w >> 1, wn = w & 1;

    const bf16_t* A = AOn + (size_t)b * NT * CH + (size_t)nt * 128 * CH;
    const bf16_t* B = Wb + (size_t)3 * CH * CH + (size_t)ct * 128 * CH;   // Wo

    f32x4 acc[4][4] = {};
    gemm_core<true>(A, B, aT, bT, acc);

    const size_t bofs = (size_t)b * CH * NT;
#pragma unroll
    for (int mi = 0; mi < 4; ++mi)
#pragma unroll
        for (int ni = 0; ni < 4; ++ni)
#pragma unroll
            for (int r = 0; r < 4; ++r) {
                int co_l = wm * 64 + mi * 16 + quad * 4 + r;
                int n_l  = wn * 64 + ni * 16 + lid;
                size_t idx = bofs + (size_t)(ct * 128 + co_l) * NT + nt * 128 + n_l;
                Zt[idx] = acc[mi][ni][r] + fc[idx];
            }
}

// ---------------------------------------------------------------------------
// stats: per (b, n) mean/rsqrt over co of Z^T.  grid (16, 8), block 256.
// ---------------------------------------------------------------------------
__global__ __launch_bounds__(256) void stats_kernel(
    const float* __restrict__ Zt, float* __restrict__ mu_buf,
    float* __restrict__ rs_buf)
{
    __shared__ float sS[1024], sQ[1024];
    const int b = blockIdx.y, n0 = blockIdx.x * 64;
    const int t = threadIdx.x, w = t >> 6, lane = t & 63;
    const int co_off = lane >> 4, n4 = lane & 15;
    const float* Zb = Zt + (size_t)b * CH * NT + n0 + n4 * 4;

    f32x4 s = {0, 0, 0, 0}, q = {0, 0, 0, 0};
    for (int it = 0; it < 32; ++it) {
        int co = w * 4 + co_off + it * 16;
        f32x4 z = *(const f32x4*)(Zb + (size_t)co * NT);
#pragma unroll
        for (int c = 0; c < 4; ++c) { s[c] += z[c]; q[c] += z[c] * z[c]; }
    }
#pragma unroll
    for (int c = 0; c < 4; ++c) { sS[t * 4 + c] = s[c]; sQ[t * 4 + c] = q[c]; }
    __syncthreads();

    if (t < 64) {
        int n4r = t >> 2, comp = t & 3;
        float ss = 0.f, qq = 0.f;
#pragma unroll
        for (int i = 0; i < 16; ++i) {
            int idx = ((i >> 2) * 64 + (i & 3) * 16 + n4r) * 4 + comp;
            ss += sS[idx]; qq += sQ[idx];
        }
        float mu  = ss * (1.0f / 512.0f);
        float var = qq * (1.0f / 512.0f) - mu * mu;
        mu_buf[(size_t)b * NT + n0 + t] = mu;
        rs_buf[(size_t)b * NT + n0 + t] = rsqrtf(var + 1e-5f);
    }
}

// ---------------------------------------------------------------------------
// apply: out[b][co][n] = (z - mu[n]) * rs[n] * gamma[co] + beta[co].
// ---------------------------------------------------------------------------
__global__ __launch_bounds__(256) void apply_kernel(
    const float* __restrict__ Zt, const float* __restrict__ mu_buf,
    const float* __restrict__ rs_buf, const float* __restrict__ gamma,
    const float* __restrict__ beta, float* __restrict__ out)
{
    const int row = blockIdx.x;           // b*512 + co
    const int co = row & 511, b = row >> 9;
    const int t = threadIdx.x;
    const float g = gamma[co], be = beta[co];
    const size_t base = (size_t)row * NT + t * 4;
    f32x4 z  = *(const f32x4*)(Zt + base);
    f32x4 mu = *(const f32x4*)(mu_buf + (size_t)b * NT + t * 4);
    f32x4 rs = *(const f32x4*)(rs_buf + (size_t)b * NT + t * 4);
    f32x4 o;
#pragma unroll
    for (int c = 0; c < 4; ++c) o[c] = (z[c] - mu[c]) * rs[c] * g + be;
    *(f32x4*)(out + base) = o;
}

// ---------------------------------------------------------------------------
extern "C" void kernel_launch(void* const* d_in, const int* in_sizes, int n_in,
                              void* d_out, int out_size, void* d_ws, size_t ws_size,
                              hipStream_t stream)
{
    (void)in_sizes; (void)n_in; (void)out_size; (void)ws_size;
    const float* fc    = (const float*)d_in[0];
    const float* fp    = (const float*)d_in[1];
    const float* fn    = (const float*)d_in[2];
    const float* Wq    = (const float*)d_in[3];
    const float* Wk    = (const float*)d_in[4];
    const float* Wv    = (const float*)d_in[5];
    const float* Wo    = (const float*)d_in[6];
    const float* gamma = (const float*)d_in[7];
    const float* beta  = (const float*)d_in[8];
    float* out = (float*)d_out;

    char* ws = (char*)d_ws;
    bf16_t* Xn  = (bf16_t*)(ws);
    bf16_t* Qn  = (bf16_t*)(ws + 16777216);
    bf16_t* Kn  = (bf16_t*)(ws + 25165824);
    bf16_t* Xc  = (bf16_t*)(ws + 41943040);
    bf16_t* AOn = Xc;
    bf16_t* Vt  = (bf16_t*)(ws + 50331648);
    bf16_t* Wb  = (bf16_t*)(ws + 67108864);
    float*  mu  = (float*)(ws + 69206016);
    float*  rs  = (float*)(ws + 69238784);
    float*  Zt  = (float*)(ws);

    prep_kernel<<<dim3(128, 24), 256, 0, stream>>>(fc, fp, fn, Xc, Xn);
    wcvt_kernel<<<dim3(256, 4), 256, 0, stream>>>(Wq, Wk, Wv, Wo, Wb);
    qkv_kernel<<<dim3(160, 8), 256, 0, stream>>>(Xc, Xn, Wb, Qn, Kn, Vt);
    attn_kernel<<<dim3(512), 256, 0, stream>>>(Qn, Kn, Vt, AOn);
    proj_kernel<<<dim3(32, 8), 256, 0, stream>>>(AOn, Wb, fc, Zt);
    stats_kernel<<<dim3(16, 8), 256, 0, stream>>>(Zt, mu, rs);
    apply_kernel<<<4096, 256, 0, stream>>>(Zt, mu, rs, gamma, beta, out);
}

// Round 3
// 230.573 us; speedup vs baseline: 1.0947x; 1.0406x over previous
//
#include <hip/hip_runtime.h>
#include <hip/hip_bf16.h>
#include <math.h>

#define NH 8
#define HD 64
#define CH 512
#define NT 1024
#define NB 8

typedef __bf16 bf16_t;
typedef bf16_t bf16x8 __attribute__((ext_vector_type(8)));
typedef bf16_t bf16x4 __attribute__((ext_vector_type(4)));
typedef float  f32x4  __attribute__((ext_vector_type(4)));
typedef float  f32x16 __attribute__((ext_vector_type(16)));
typedef unsigned u32x4 __attribute__((ext_vector_type(4)));

#define MFMA16(a, b, c) __builtin_amdgcn_mfma_f32_16x16x32_bf16((a), (b), (c), 0, 0, 0)
#define MFMA32(a, b, c) __builtin_amdgcn_mfma_f32_32x32x16_bf16((a), (b), (c), 0, 0, 0)
#define EXP2(x) __builtin_amdgcn_exp2f(x)

__device__ __forceinline__ void gload16(const void* g, void* l) {
    __builtin_amdgcn_global_load_lds(
        (const __attribute__((address_space(1))) void*)g,
        (__attribute__((address_space(3))) void*)l, 16, 0, 0);
}

// pack two f32 -> one dword of 2x bf16 (no builtin on gfx950; T12 recipe)
__device__ __forceinline__ unsigned cvtpk(float lo, float hi) {
    unsigned r;
    asm("v_cvt_pk_bf16_f32 %0, %1, %2" : "=v"(r) : "v"(lo), "v"(hi));
    return r;
}

// v_permlane32_swap_b32: a' = {a.lo32, b.lo32}, b' = {a.hi32, b.hi32}
__device__ __forceinline__ void plswap(unsigned& a, unsigned& b) {
    asm("v_permlane32_swap_b32 %0, %1" : "+v"(a), "+v"(b));
}

// ---------------------------------------------------------------------------
// prep: fp32 [C][N] -> bf16 [N][C] transpose (per 64x64 tile).
// grid (128, 24): x = tile (c-tile = x&7, n-tile = x>>3); y: b = y/3, ft = y%3
// ---------------------------------------------------------------------------
__global__ __launch_bounds__(256) void prep_kernel(
    const float* __restrict__ fc, const float* __restrict__ fp,
    const float* __restrict__ fn, bf16_t* __restrict__ Xc,
    bf16_t* __restrict__ Xn)
{
    __shared__ __align__(16) bf16_t tile[64 * 64];
    const int t = threadIdx.x;
    const int y = blockIdx.y;
    const int b = y / 3, ft = y % 3;
    const int c0 = (blockIdx.x & 7) * 64;
    const int n0 = (blockIdx.x >> 3) * 64;

    const float* src; bf16_t* dst;
    if (ft == 0)      { src = fc + (size_t)b * CH * NT; dst = Xc + (size_t)b * NT * CH; }
    else if (ft == 1) { src = fp + (size_t)b * CH * NT; dst = Xn + (size_t)b * 2 * NT * CH; }
    else              { src = fn + (size_t)b * CH * NT; dst = Xn + (size_t)b * 2 * NT * CH + (size_t)NT * CH; }

    const int nb = t & 15, cb = t >> 4;   // 4-wide chunks
    float4 ld[4];
#pragma unroll
    for (int i = 0; i < 4; ++i)
        ld[i] = *(const float4*)(src + (size_t)(c0 + cb * 4 + i) * NT + n0 + nb * 4);
    const float* lf = (const float*)ld;
#pragma unroll
    for (int j = 0; j < 4; ++j) {
        int n = nb * 4 + j;
        int v = (n >> 2) & 14;            // even -> bf16x8 readback stays contiguous
        bf16x4 wv = { (bf16_t)lf[0 * 4 + j], (bf16_t)lf[1 * 4 + j],
                      (bf16_t)lf[2 * 4 + j], (bf16_t)lf[3 * 4 + j] };
        *(bf16x4*)(tile + n * 64 + ((cb ^ v) * 4)) = wv;
    }
    __syncthreads();
#pragma unroll
    for (int i = 0; i < 2; ++i) {
        int gid = t + i * 256;            // 512 chunks of 16B
        int n = gid >> 3, c16 = gid & 7;
        int v = (n >> 2) & 14;
        bf16x8 val = *(const bf16x8*)(tile + n * 64 + (((2 * c16) ^ v) * 4));
        *(bf16x8*)(dst + (size_t)(n0 + n) * CH + c0 + c16 * 8) = val;
    }
}

// weights fp32 -> bf16, grid (256, 4); also zeroes the LN sum/sumsq buffers
__global__ __launch_bounds__(256) void wcvt_kernel(
    const float* __restrict__ Wq, const float* __restrict__ Wk,
    const float* __restrict__ Wv, const float* __restrict__ Wo,
    bf16_t* __restrict__ Wb, float* __restrict__ SQz)
{
    const int m = blockIdx.y;
    const float* src = (m == 0) ? Wq : (m == 1) ? Wk : (m == 2) ? Wv : Wo;
    bf16_t* dst = Wb + (size_t)m * CH * CH;
    int gid = blockIdx.x * 256 + threadIdx.x;      // 65536 float4 per matrix
    float4 v = *(const float4*)(src + (size_t)gid * 4);
    bf16x4 o = { (bf16_t)v.x, (bf16_t)v.y, (bf16_t)v.z, (bf16_t)v.w };
    *(bf16x4*)(dst + (size_t)gid * 4) = o;
    if (m == 0 && blockIdx.x < 16) {               // 16*256*16B = 64KB (sum+sumsq)
        f32x4 zz = {0.f, 0.f, 0.f, 0.f};
        *(f32x4*)(SQz + (size_t)(blockIdx.x * 256 + threadIdx.x) * 4) = zz;
    }
}

// ---------------------------------------------------------------------------
// gemm_core: 128x128 tile, K=512, BK=32, all-bf16, global_load_lds staging.
// ---------------------------------------------------------------------------
template <bool SWAP>
__device__ __forceinline__ void gemm_core(const bf16_t* __restrict__ A,
                                          const bf16_t* __restrict__ B,
                                          bf16_t* aT, bf16_t* bT,
                                          f32x4 acc[4][4])
{
    const int t = threadIdx.x, w = t >> 6, lane = t & 63;
    const int lid = lane & 15, quad = lane >> 4;
    const int wm = w >> 1, wn = w & 1;
    const int l4 = lane >> 2, k4 = lane & 3;

    for (int kt = 0; kt < 16; ++kt) {
        const int k0 = kt * 32;
        __syncthreads();
#pragma unroll
        for (int i = 0; i < 2; ++i) {
            int q = w * 2 + i;                       // chunk 0..7 (16 rows each)
            int row = q * 16 + l4;
            int kk = k4 ^ ((row >> 1) & 3);
            gload16(A + (size_t)row * CH + k0 + kk * 8, aT + q * 512);
            gload16(B + (size_t)row * CH + k0 + kk * 8, bT + q * 512);
        }
        __syncthreads();

        const bf16_t* mT = SWAP ? bT : aT;
        const bf16_t* nT = SWAP ? aT : bT;
        bf16x8 mf[4], nf[4];
#pragma unroll
        for (int i = 0; i < 4; ++i) {
            int row = wm * 64 + i * 16 + lid;
            int kw = quad ^ ((row >> 1) & 3);
            mf[i] = *(const bf16x8*)(mT + row * 32 + kw * 8);
        }
#pragma unroll
        for (int i = 0; i < 4; ++i) {
            int row = wn * 64 + i * 16 + lid;
            int kw = quad ^ ((row >> 1) & 3);
            nf[i] = *(const bf16x8*)(nT + row * 32 + kw * 8);
        }
#pragma unroll
        for (int mi = 0; mi < 4; ++mi)
#pragma unroll
            for (int ni = 0; ni < 4; ++ni)
                acc[mi][ni] = MFMA16(mf[mi], nf[ni], acc[mi][ni]);
    }
}

// ---------------------------------------------------------------------------
// qkv: grid (160, 8).  bx<32: Q; 32..95: K; 96..159: V (SWAP, writes Vt[co][key])
// ---------------------------------------------------------------------------
__global__ __launch_bounds__(256) void qkv_kernel(
    const bf16_t* __restrict__ Xc, const bf16_t* __restrict__ Xn,
    const bf16_t* __restrict__ Wb,
    bf16_t* __restrict__ Qn, bf16_t* __restrict__ Kn, bf16_t* __restrict__ Vt)
{
    __shared__ __align__(16) bf16_t aT[128 * 32];
    __shared__ __align__(16) bf16_t bT[128 * 32];
    const int bx = blockIdx.x, b = blockIdx.y;
    const int t = threadIdx.x, w = t >> 6, lane = t & 63;
    const int lid = lane & 15, quad = lane >> 4;
    const int wm = w >> 1, wn = w & 1;
    const float QSC = 0.125f * 1.44269504f;

    f32x4 acc[4][4] = {};

    if (bx < 96) {                        // Q or K job
        const bf16_t* A; const bf16_t* B; bf16_t* O; float scale;
        if (bx < 32) {
            int nt = bx >> 2, ct = bx & 3;
            A = Xc + (size_t)b * NT * CH + (size_t)nt * 128 * CH;
            B = Wb + (size_t)0 * CH * CH + (size_t)ct * 128 * CH;
            O = Qn + (size_t)b * NT * CH + (size_t)nt * 128 * CH + ct * 128;
            scale = QSC;
        } else {
            int j = bx - 32, nt = j >> 2, ct = j & 3;
            A = Xn + (size_t)b * 2 * NT * CH + (size_t)nt * 128 * CH;
            B = Wb + (size_t)1 * CH * CH + (size_t)ct * 128 * CH;
            O = Kn + (size_t)b * 2 * NT * CH + (size_t)nt * 128 * CH + ct * 128;
            scale = 1.0f;
        }
        gemm_core<false>(A, B, aT, bT, acc);
#pragma unroll
        for (int mi = 0; mi < 4; ++mi)
#pragma unroll
            for (int ni = 0; ni < 4; ++ni)
#pragma unroll
                for (int r = 0; r < 4; ++r) {
                    int n  = wm * 64 + mi * 16 + quad * 4 + r;
                    int co = wn * 64 + ni * 16 + lid;
                    O[(size_t)n * CH + co] = (bf16_t)(acc[mi][ni][r] * scale);
                }
    } else {                              // V job -> Vt[co][key]
        int j = bx - 96, nt = j >> 2, ct = j & 3;
        const bf16_t* A = Xn + (size_t)b * 2 * NT * CH + (size_t)nt * 128 * CH;
        const bf16_t* B = Wb + (size_t)2 * CH * CH + (size_t)ct * 128 * CH;
        bf16_t* O = Vt + (size_t)b * CH * 2 * NT + (size_t)ct * 128 * 2 * NT + nt * 128;
        gemm_core<true>(A, B, aT, bT, acc);
#pragma unroll
        for (int mi = 0; mi < 4; ++mi)
#pragma unroll
            for (int ni = 0; ni < 4; ++ni)
#pragma unroll
                for (int r = 0; r < 4; ++r) {
                    int co_l  = wm * 64 + mi * 16 + quad * 4 + r;
                    int key_l = wn * 64 + ni * 16 + lid;
                    O[(size_t)co_l * (2 * NT) + key_l] = (bf16_t)acc[mi][ni][r];
                }
    }
}

// ---------------------------------------------------------------------------
// attn v3: zero LDS / zero barriers in the main loop.
// K/V are L2-resident (FETCH_SIZE proved it) -> MFMA fragments gather-load
// directly from global (same per-lane pattern the LDS path produced). Q is
// gather-loaded once into registers. P stays in registers (cvt_pk+permlane).
// Waves free-run over all 16 key-tiles; LDS (56KB) only backs the epilogue.
// ---------------------------------------------------------------------------
__global__ __launch_bounds__(256, 2) void attn_kernel(
    const bf16_t* __restrict__ Qn, const bf16_t* __restrict__ Kn,
    const bf16_t* __restrict__ Vt, bf16_t* __restrict__ AOn)
{
    __shared__ __align__(16) char smem[55808];
    float*  const scr_all = (float*)smem;            // 2 x 4352 f32 (34816B)
    bf16_t* const obuf    = (bf16_t*)(smem + 36864); // [128][72] bf16
    float*  const l_scr   = (float*)(smem + 55296);  // 128 f32

    const int t = threadIdx.x;
    const int w = t >> 6, lane = t & 63;
    const int wq = w >> 1, wk = w & 1;
    const int l31 = lane & 31, h = lane >> 5;

    // XCD-aware decode: all 8 q-tiles of one (b,h) share one XCD's L2.
    const int bid = blockIdx.x;
    const int xcd = bid & 7, ii = bid >> 3;
    const int grp = xcd * 8 + (ii >> 3);
    const int qt  = ii & 7;
    const int b = grp >> 3, hh = grp & 7;
    const int q0 = qt * 128;

    const bf16_t* Qb  = Qn + ((size_t)b * NT + q0) * CH + hh * HD;
    const bf16_t* Kb  = Kn + (size_t)b * 2 * NT * CH + hh * HD;
    const bf16_t* Vtb = Vt + ((size_t)b * CH + hh * HD) * (2 * NT);
    bf16_t* AOb = AOn + ((size_t)b * NT + q0) * CH + hh * HD;

    // per-lane fragment base pointers (16B granules)
    const bf16_t* Qrow = Qb  + (size_t)(wq * 64 + l31) * CH + h * 8;
    const bf16_t* Krow = Kb  + (size_t)(wk * 64 + l31) * CH + h * 8;
    const bf16_t* Vrow = Vtb + (size_t)l31 * (2 * NT) + wk * 64 + h * 8;

    // Q fragments: B-operand, lane(l31=q, h) elem e = Q[q][ks*16 + 8h + e]
    bf16x8 qf[2][4];
#pragma unroll
    for (int nf = 0; nf < 2; ++nf)
#pragma unroll
        for (int ks = 0; ks < 4; ++ks)
            qf[nf][ks] = *(const bf16x8*)(Qrow + (size_t)nf * 32 * CH + ks * 16);

    f32x16 o[2][2] = {};
    float lpart[2] = {0.f, 0.f};

    for (int kt = 0; kt < 16; ++kt) {
        const size_t kb = (size_t)kt * 128;

        // K fragments: A-operand, lane(l31=key, h) elem e = K[key][ks*16+8h+e]
        bf16x8 kf[2][4];
#pragma unroll
        for (int mf = 0; mf < 2; ++mf)
#pragma unroll
            for (int ks = 0; ks < 4; ++ks)
                kf[mf][ks] = *(const bf16x8*)(Krow + (kb + mf * 32) * CH + ks * 16);

        f32x16 s[2][2] = {};
        __builtin_amdgcn_s_setprio(1);
#pragma unroll
        for (int ks = 0; ks < 4; ++ks)
#pragma unroll
            for (int mf = 0; mf < 2; ++mf)
#pragma unroll
                for (int nf = 0; nf < 2; ++nf)
                    s[mf][nf] = MFMA32(kf[mf][ks], qf[nf][ks], s[mf][nf]);
        __builtin_amdgcn_s_setprio(0);

        // V fragments (independent of softmax; L2 latency hides under exp)
        bf16x8 vf[2][4];
#pragma unroll
        for (int df = 0; df < 2; ++df)
#pragma unroll
            for (int ks = 0; ks < 4; ++ks)
                vf[df][ks] = *(const bf16x8*)(Vrow + (size_t)df * 32 * (2 * NT) + kb + ks * 16);

        // softmax(mf) in registers, then PV(mf)
#pragma unroll
        for (int mf = 0; mf < 2; ++mf) {
            bf16x8 pfrag[2][2];                  // [nf][fi]  fi: 16-key half
#pragma unroll
            for (int nf = 0; nf < 2; ++nf) {
                float p[16];
#pragma unroll
                for (int r = 0; r < 16; ++r) p[r] = EXP2(s[mf][nf][r]);
                lpart[nf] += ((p[0] + p[1]) + (p[2] + p[3]))
                           + ((p[4] + p[5]) + (p[6] + p[7]))
                           + ((p[8] + p[9]) + (p[10] + p[11]))
                           + ((p[12] + p[13]) + (p[14] + p[15]));
                unsigned a0 = cvtpk(p[0], p[1]),   b0 = cvtpk(p[4], p[5]);
                unsigned a1 = cvtpk(p[2], p[3]),   b1 = cvtpk(p[6], p[7]);
                unsigned a2 = cvtpk(p[8], p[9]),   b2 = cvtpk(p[12], p[13]);
                unsigned a3 = cvtpk(p[10], p[11]), b3 = cvtpk(p[14], p[15]);
                plswap(a0, b0); plswap(a1, b1); plswap(a2, b2); plswap(a3, b3);
                u32x4 f0 = { a0, a1, b0, b1 };
                u32x4 f1 = { a2, a3, b2, b3 };
                pfrag[nf][0] = __builtin_bit_cast(bf16x8, f0);
                pfrag[nf][1] = __builtin_bit_cast(bf16x8, f1);
            }
            __builtin_amdgcn_s_setprio(1);
#pragma unroll
            for (int fi = 0; fi < 2; ++fi) {
                const int ks = mf * 2 + fi;
#pragma unroll
                for (int df = 0; df < 2; ++df)
#pragma unroll
                    for (int nf = 0; nf < 2; ++nf)
                        o[df][nf] = MFMA32(vf[df][ks], pfrag[nf][fi], o[df][nf]);
            }
            __builtin_amdgcn_s_setprio(0);
        }
    }

    // ---- epilogue: combine wk halves, normalize, store --------------------
    float l2[2];
#pragma unroll
    for (int nf = 0; nf < 2; ++nf)
        l2[nf] = lpart[nf] + __shfl_xor(lpart[nf], 32);

    if (wk == 1) {
        float* scr = scr_all + wq * 4352;
#pragma unroll
        for (int df = 0; df < 2; ++df)
#pragma unroll
            for (int nf = 0; nf < 2; ++nf) {
                int qrow = nf * 32 + l31;
#pragma unroll
                for (int g = 0; g < 4; ++g) {
                    int d = df * 32 + 8 * g + 4 * h;
                    f32x4 v = { o[df][nf][4 * g + 0], o[df][nf][4 * g + 1],
                                o[df][nf][4 * g + 2], o[df][nf][4 * g + 3] };
                    *(f32x4*)(scr + qrow * 68 + d) = v;
                }
            }
        if (h == 0) {
            l_scr[wq * 64 + 0 * 32 + l31] = l2[0];
            l_scr[wq * 64 + 1 * 32 + l31] = l2[1];
        }
    }
    __syncthreads();

    if (wk == 0) {
        const float* scr = scr_all + wq * 4352;
        float inv[2];
#pragma unroll
        for (int nf = 0; nf < 2; ++nf)
            inv[nf] = 1.0f / (l2[nf] + l_scr[wq * 64 + nf * 32 + l31]);
#pragma unroll
        for (int df = 0; df < 2; ++df)
#pragma unroll
            for (int nf = 0; nf < 2; ++nf) {
                int qrow = nf * 32 + l31;
#pragma unroll
                for (int g = 0; g < 4; ++g) {
                    int d = df * 32 + 8 * g + 4 * h;
                    f32x4 part = *(const f32x4*)(scr + qrow * 68 + d);
                    bf16x4 ov = {
                        (bf16_t)((o[df][nf][4 * g + 0] + part.x) * inv[nf]),
                        (bf16_t)((o[df][nf][4 * g + 1] + part.y) * inv[nf]),
                        (bf16_t)((o[df][nf][4 * g + 2] + part.z) * inv[nf]),
                        (bf16_t)((o[df][nf][4 * g + 3] + part.w) * inv[nf]) };
                    int qg = wq * 64 + qrow;
                    *(bf16x4*)(obuf + qg * 72 + (d ^ (qg & 24))) = ov;
                }
            }
    }
    __syncthreads();

#pragma unroll
    for (int i = 0; i < 4; ++i) {
        int gid = t + i * 256;
        int qr = gid >> 3, c8 = (gid & 7) * 8;
        *(bf16x8*)(AOb + (size_t)qr * CH + c8) =
            *(const bf16x8*)(obuf + qr * 72 + (c8 ^ (qr & 24)));
    }
}

// ---------------------------------------------------------------------------
// proj: Z^T[b][co][n] = (AO @ Wo^T)^T + f_curr[b][co][n]  (fp32). grid (32, 8)
// Fused LN stats: block reduces its 128-co slab per n, atomicAdd sum/sumsq.
// ---------------------------------------------------------------------------
__global__ __launch_bounds__(256) void proj_kernel(
    const bf16_t* __restrict__ AOn, const bf16_t* __restrict__ Wb,
    const float* __restrict__ fc, float* __restrict__ Zt,
    float* __restrict__ Ssum, float* __restrict__ Ssq)
{
    __shared__ __align__(16) bf16_t aT[128 * 32];
    __shared__ __align__(16) bf16_t bT[128 * 32];
    const int bx = blockIdx.x, b = blockIdx.y;
    const int nt = bx >> 2, ct = bx & 3;
    const int t = threadIdx.x, w = t >> 6, lane = t & 63;
    const int lid = lane & 15, quad = lane >> 4;
    const int wm = w >> 1, wn = w & 1;

    const bf16_t* A = AOn + (size_t)b * NT * CH + (size_t)nt * 128 * CH;
    const bf16_t* B = Wb + (size_t)3 * CH * CH + (size_t)ct * 128 * CH;   // Wo

    f32x4 acc[4][4] = {};
    gemm_core<true>(A, B, aT, bT, acc);

    const size_t bofs = (size_t)b * CH * NT;
    float sP[4] = {0.f, 0.f, 0.f, 0.f}, qP[4] = {0.f, 0.f, 0.f, 0.f};
#pragma unroll
    for (int mi = 0; mi < 4; ++mi)
#pragma unroll
        for (int ni = 0; ni < 4; ++ni)
#pragma unroll
            for (int r = 0; r < 4; ++r) {
                int co_l = wm * 64 + mi * 16 + quad * 4 + r;
                int n_l  = wn * 64 + ni * 16 + lid;
                size_t idx = bofs + (size_t)(ct * 128 + co_l) * NT + nt * 128 + n_l;
                float z = acc[mi][ni][r] + fc[idx];
                Zt[idx] = z;
                sP[ni] += z;
                qP[ni] += z * z;
            }
    // reduce over quad (co sub-blocks) within wave
#pragma unroll
    for (int ni = 0; ni < 4; ++ni) {
        sP[ni] += __shfl_xor(sP[ni], 16);  sP[ni] += __shfl_xor(sP[ni], 32);
        qP[ni] += __shfl_xor(qP[ni], 16);  qP[ni] += __shfl_xor(qP[ni], 32);
    }
    __syncthreads();                      // all frag reads of aT done
    float* sRed = (float*)aT;             // 256 f32
    float* qRed = sRed + 256;
    if (quad == 0) {
#pragma unroll
        for (int ni = 0; ni < 4; ++ni) {
            sRed[w * 64 + ni * 16 + lid] = sP[ni];
            qRed[w * 64 + ni * 16 + lid] = qP[ni];
        }
    }
    __syncthreads();
    if (t < 128) {                        // n_l = t; waves w=wn and w=2+wn
        float s = sRed[t] + sRed[128 + t];
        float q = qRed[t] + qRed[128 + t];
        atomicAdd(&Ssum[(size_t)b * NT + nt * 128 + t], s);
        atomicAdd(&Ssq [(size_t)b * NT + nt * 128 + t], q);
    }
}

// ---------------------------------------------------------------------------
// apply: out[b][co][n] = (z - mu[n]) * rs[n] * gamma[co] + beta[co].
// mu/rs computed inline from fused sum/sumsq.
// ---------------------------------------------------------------------------
__global__ __launch_bounds__(256) void apply_kernel(
    const float* __restrict__ Zt, const float* __restrict__ Ssum,
    const float* __restrict__ Ssq, const float* __restrict__ gamma,
    const float* __restrict__ beta, float* __restrict__ out)
{
    const int row = blockIdx.x;           // b*512 + co
    const int co = row & 511, b = row >> 9;
    const int t = threadIdx.x;
    const float g = gamma[co], be = beta[co];
    const size_t base = (size_t)row * NT + t * 4;
    f32x4 z  = *(const f32x4*)(Zt + base);
    f32x4 S  = *(const f32x4*)(Ssum + (size_t)b * NT + t * 4);
    f32x4 Q2 = *(const f32x4*)(Ssq  + (size_t)b * NT + t * 4);
    f32x4 o;
#pragma unroll
    for (int c = 0; c < 4; ++c) {
        float mu  = S[c] * (1.0f / 512.0f);
        float var = Q2[c] * (1.0f / 512.0f) - mu * mu;
        float rs  = rsqrtf(var + 1e-5f);
        o[c] = (z[c] - mu) * rs * g + be;
    }
    *(f32x4*)(out + base) = o;
}

// ---------------------------------------------------------------------------
extern "C" void kernel_launch(void* const* d_in, const int* in_sizes, int n_in,
                              void* d_out, int out_size, void* d_ws, size_t ws_size,
                              hipStream_t stream)
{
    (void)in_sizes; (void)n_in; (void)out_size; (void)ws_size;
    const float* fc    = (const float*)d_in[0];
    const float* fp    = (const float*)d_in[1];
    const float* fn    = (const float*)d_in[2];
    const float* Wq    = (const float*)d_in[3];
    const float* Wk    = (const float*)d_in[4];
    const float* Wv    = (const float*)d_in[5];
    const float* Wo    = (const float*)d_in[6];
    const float* gamma = (const float*)d_in[7];
    const float* beta  = (const float*)d_in[8];
    float* out = (float*)d_out;

    char* ws = (char*)d_ws;
    bf16_t* Xn  = (bf16_t*)(ws);
    bf16_t* Qn  = (bf16_t*)(ws + 16777216);
    bf16_t* Kn  = (bf16_t*)(ws + 25165824);
    bf16_t* Xc  = (bf16_t*)(ws + 41943040);
    bf16_t* AOn = Xc;
    bf16_t* Vt  = (bf16_t*)(ws + 50331648);
    bf16_t* Wb  = (bf16_t*)(ws + 67108864);
    float*  Ssum = (float*)(ws + 69206016);
    float*  Ssq  = (float*)(ws + 69238784);
    float*  Zt  = (float*)(ws);

    prep_kernel<<<dim3(128, 24), 256, 0, stream>>>(fc, fp, fn, Xc, Xn);
    wcvt_kernel<<<dim3(256, 4), 256, 0, stream>>>(Wq, Wk, Wv, Wo, Wb, Ssum);
    qkv_kernel<<<dim3(160, 8), 256, 0, stream>>>(Xc, Xn, Wb, Qn, Kn, Vt);
    attn_kernel<<<dim3(512), 256, 0, stream>>>(Qn, Kn, Vt, AOn);
    proj_kernel<<<dim3(32, 8), 256, 0, stream>>>(AOn, Wb, fc, Zt, Ssum, Ssq);
    apply_kernel<<<4096, 256, 0, stream>>>(Zt, Ssum, Ssq, gamma, beta, out);
}